// Round 1
// baseline (6944.297 us; speedup 1.0000x reference)
//
#include <hip/hip_runtime.h>
#include <hip/hip_bf16.h>

#define Bsz  1024
#define Hsz  1024
#define Isz  69
#define SRCn 50
#define Tn   74
#define XPAD 96
#define KPAD 1120               // 1024 (h) + 96 (x, zero-padded from 69)
#define LDSTR 40                // LDS row stride in bf16 elems (80 B, 16B-aligned, breaks bank conflicts)
#define BOFF (64*LDSTR)         // B tiles start after the 64-row A tile
#define BUFE (256*LDSTR)        // (64 A rows + 3*64 B rows) * stride

typedef short  short8 __attribute__((ext_vector_type(8)));
typedef float  f32x4  __attribute__((ext_vector_type(4)));

__device__ __forceinline__ unsigned short f2bf(float f) {
    unsigned u = __float_as_uint(f);
    return (unsigned short)((u + 0x7fffu + ((u >> 16) & 1u)) >> 16);  // RNE
}

__global__ void init_kernel(float* __restrict__ h0, float* __restrict__ logit,
                            const float* __restrict__ fc2_b) {
    unsigned idx = blockIdx.x * blockDim.x + threadIdx.x;
    if (idx < (unsigned)(Bsz * Hsz)) h0[idx] = 0.f;
    if (idx < (unsigned)Bsz) logit[idx] = fc2_b[0];
}

// wpack[g*1024+j][k] = k<1024 ? w_hh[g*1024+j][k] : (k<1093 ? w_ih[g*1024+j][k-1024] : 0), bf16
__global__ void pack_weights(const float* __restrict__ w_ih, const float* __restrict__ w_hh,
                             unsigned short* __restrict__ wpack) {
    unsigned idx = blockIdx.x * blockDim.x + threadIdx.x;
    if (idx >= 3u * 1024u * KPAD) return;
    unsigned k = idx % KPAD;
    unsigned row = idx / KPAD;
    float v = 0.f;
    if (k < 1024u)              v = w_hh[(size_t)row * 1024u + k];
    else if (k < 1024u + Isz)   v = w_ih[(size_t)row * Isz + (k - 1024u)];
    wpack[idx] = f2bf(v);
}

// frames[t][b][i(96 padded)] = all_frame[b][t][i]
__global__ void pack_frames(const float* __restrict__ enc, const float* __restrict__ dec,
                            float* __restrict__ frames) {
    unsigned idx = blockIdx.x * blockDim.x + threadIdx.x;
    if (idx >= (unsigned)(Tn * Bsz * XPAD)) return;
    unsigned i = idx % XPAD;
    unsigned rem = idx / XPAD;
    unsigned b = rem % Bsz;
    unsigned t = rem / Bsz;
    float v = 0.f;
    if (i < Isz)
        v = (t < SRCn) ? enc[((size_t)b * SRCn + t) * Isz + i]
                       : dec[((size_t)b * (Tn - SRCn) + (t - SRCn)) * Isz + i];
    frames[idx] = v;
}

// Fused GRU step: h_out = GRUCell(x, h_in).
// Grid 256 (16 m-tiles x 16 n-tiles of 64), block 256 (4 waves, wave-tile 64Mx16N x 3 gates).
// K-concat GEMM over [h | x] (K=1120); n-gate accumulates h-part and x-part separately.
__launch_bounds__(256)
__global__ void gru_step(const float* __restrict__ h_in, const float* __restrict__ x,
                         const unsigned short* __restrict__ wpack,
                         const float* __restrict__ b_ih, const float* __restrict__ b_hh,
                         float* __restrict__ h_out)
{
    __shared__ unsigned short lds[2 * BUFE];
    const int t    = threadIdx.x;
    const int bm   = blockIdx.x & 15;
    const int bn   = blockIdx.x >> 4;
    const int wave = t >> 6;
    const int lane = t & 63;
    const int quad = lane >> 4;
    const int l16  = lane & 15;
    const int srow = t >> 2;          // staging row 0..63
    const int sc   = (t & 3) * 8;     // staging col 0,8,16,24

    f32x4 accR[4], accZ[4], accNH[4], accNI[4];
#pragma unroll
    for (int i = 0; i < 4; ++i) {
        accR[i]  = (f32x4){0.f, 0.f, 0.f, 0.f};
        accZ[i]  = (f32x4){0.f, 0.f, 0.f, 0.f};
        accNH[i] = (f32x4){0.f, 0.f, 0.f, 0.f};
        accNI[i] = (f32x4){0.f, 0.f, 0.f, 0.f};
    }

    const unsigned short* wb_base = wpack + (size_t)(bn * 64 + srow) * KPAD + sc;
    const float* ha_base = h_in + (size_t)(bm * 64 + srow) * 1024 + sc;
    const float* xa_base = x    + (size_t)(bm * 64 + srow) * XPAD + sc;

    float4 pa0, pa1;
    uint4  pb0, pb1, pb2;

    auto prefetch = [&](int kt) {
        int k0 = kt * 32;
        const float* ap = (k0 < 1024) ? (ha_base + k0) : (xa_base + (k0 - 1024));
        pa0 = *(const float4*)ap;
        pa1 = *(const float4*)(ap + 4);
        const unsigned short* wp = wb_base + k0;
        pb0 = *(const uint4*)(wp);
        pb1 = *(const uint4*)(wp + (size_t)1024 * KPAD);
        pb2 = *(const uint4*)(wp + (size_t)2048 * KPAD);
    };
    auto stage = [&](int buf) {
        unsigned short* base = lds + buf * BUFE;
        uint4 av;
        av.x = (unsigned)f2bf(pa0.x) | ((unsigned)f2bf(pa0.y) << 16);
        av.y = (unsigned)f2bf(pa0.z) | ((unsigned)f2bf(pa0.w) << 16);
        av.z = (unsigned)f2bf(pa1.x) | ((unsigned)f2bf(pa1.y) << 16);
        av.w = (unsigned)f2bf(pa1.z) | ((unsigned)f2bf(pa1.w) << 16);
        *(uint4*)(base + srow * LDSTR + sc) = av;
        unsigned short* bb = base + BOFF + srow * LDSTR + sc;
        *(uint4*)(bb)              = pb0;
        *(uint4*)(bb +  64*LDSTR)  = pb1;
        *(uint4*)(bb + 128*LDSTR)  = pb2;
    };
    auto compute = [&](int kt) {
        const unsigned short* base = lds + (kt & 1) * BUFE;
        const unsigned short* bp = base + BOFF + (wave * 16 + l16) * LDSTR + quad * 8;
        short8 b0 = *(const short8*)(bp);
        short8 b1 = *(const short8*)(bp +  64*LDSTR);
        short8 b2 = *(const short8*)(bp + 128*LDSTR);
        const unsigned short* apb = base + l16 * LDSTR + quad * 8;
        if (kt < 32) {
#pragma unroll
            for (int mt = 0; mt < 4; ++mt) {
                short8 a = *(const short8*)(apb + mt * 16 * LDSTR);
                accR[mt]  = __builtin_amdgcn_mfma_f32_16x16x32_bf16(a, b0, accR[mt],  0, 0, 0);
                accZ[mt]  = __builtin_amdgcn_mfma_f32_16x16x32_bf16(a, b1, accZ[mt],  0, 0, 0);
                accNH[mt] = __builtin_amdgcn_mfma_f32_16x16x32_bf16(a, b2, accNH[mt], 0, 0, 0);
            }
        } else {
#pragma unroll
            for (int mt = 0; mt < 4; ++mt) {
                short8 a = *(const short8*)(apb + mt * 16 * LDSTR);
                accR[mt]  = __builtin_amdgcn_mfma_f32_16x16x32_bf16(a, b0, accR[mt],  0, 0, 0);
                accZ[mt]  = __builtin_amdgcn_mfma_f32_16x16x32_bf16(a, b1, accZ[mt],  0, 0, 0);
                accNI[mt] = __builtin_amdgcn_mfma_f32_16x16x32_bf16(a, b2, accNI[mt], 0, 0, 0);
            }
        }
    };

    prefetch(0);
    stage(0);
    __syncthreads();
#pragma unroll 1
    for (int kt = 0; kt < 35; ++kt) {
        if (kt < 34) prefetch(kt + 1);
        compute(kt);
        if (kt < 34) {
            stage((kt + 1) & 1);
            __syncthreads();
        }
    }

    // Epilogue: gates + state update. C/D layout: col(n)=lane&15, row(m)=quad*4+reg.
    const int j = bn * 64 + wave * 16 + l16;
    const float bir = b_ih[j],        bhr = b_hh[j];
    const float biz = b_ih[1024 + j], bhz = b_hh[1024 + j];
    const float bin_= b_ih[2048 + j], bhn = b_hh[2048 + j];
#pragma unroll
    for (int mt = 0; mt < 4; ++mt) {
#pragma unroll
        for (int r = 0; r < 4; ++r) {
            int m = bm * 64 + mt * 16 + quad * 4 + r;
            float gr = accR[mt][r] + bir + bhr;
            float gz = accZ[mt][r] + biz + bhz;
            float rg = 1.f / (1.f + __expf(-gr));
            float zg = 1.f / (1.f + __expf(-gz));
            float nx = accNI[mt][r] + bin_ + rg * (accNH[mt][r] + bhn);
            nx = fminf(30.f, fmaxf(-30.f, nx));
            float e  = __expf(-2.f * nx);
            float ng = (1.f - e) / (1.f + e);
            float hp = h_in[(size_t)m * 1024 + j];
            h_out[(size_t)m * 1024 + j] = (1.f - zg) * ng + zg * hp;
        }
    }
}

// Decode epilogue: out = xprev + h @ fc1_w.T + fc1_b; writes padded xout; accumulates fc2 logit.
__launch_bounds__(256)
__global__ void fc1_step(const float* __restrict__ h, const float* __restrict__ xprev,
                         const float* __restrict__ fc1_w, const float* __restrict__ fc1_b,
                         const float* __restrict__ fc2_w, float* __restrict__ xout,
                         float* __restrict__ logit, int step)
{
    __shared__ float hs[1024];
    const int b = blockIdx.x;
    const int t = threadIdx.x;
    ((float4*)hs)[t] = ((const float4*)(h + (size_t)b * 1024))[t];
    __syncthreads();
    const int wave = t >> 6, lane = t & 63;
    float lp = 0.f;
    for (int i = wave; i < Isz; i += 4) {
        const float* wr = fc1_w + (size_t)i * 1024 + lane;
        float p = 0.f;
#pragma unroll
        for (int jj = 0; jj < 16; ++jj) p += hs[lane + (jj << 6)] * wr[jj << 6];
#pragma unroll
        for (int off = 32; off > 0; off >>= 1) p += __shfl_down(p, off, 64);
        if (lane == 0) {
            float o = xprev[(size_t)b * XPAD + i] + p + fc1_b[i];
            xout[(size_t)b * XPAD + i] = o;
            lp += fc2_w[step * Isz + i] * o;
        }
    }
    if (lane == 0) atomicAdd(logit + b, lp);
    if (t < XPAD - Isz) xout[(size_t)b * XPAD + Isz + t] = 0.f;
}

__global__ void final_kernel(const float* __restrict__ logit, float* __restrict__ out) {
    int i = blockIdx.x * blockDim.x + threadIdx.x;
    if (i < Bsz) out[i] = 1.f / (1.f + __expf(-logit[i]));
}

extern "C" void kernel_launch(void* const* d_in, const int* in_sizes, int n_in,
                              void* d_out, int out_size, void* d_ws, size_t ws_size,
                              hipStream_t stream)
{
    const float* enc   = (const float*)d_in[0];
    const float* dec   = (const float*)d_in[1];
    const float* w_ih  = (const float*)d_in[2];
    const float* w_hh  = (const float*)d_in[3];
    const float* b_ih  = (const float*)d_in[4];
    const float* b_hh  = (const float*)d_in[5];
    const float* fc1_w = (const float*)d_in[6];
    const float* fc1_b = (const float*)d_in[7];
    const float* fc2_w = (const float*)d_in[8];
    const float* fc2_b = (const float*)d_in[9];
    float* out = (float*)d_out;

    char* ws = (char*)d_ws;
    size_t off = 0;
    auto alloc = [&](size_t bytes) -> void* {
        void* p = ws + off;
        off += (bytes + 255) & ~(size_t)255;
        return p;
    };
    unsigned short* wpack = (unsigned short*)alloc((size_t)3 * 1024 * KPAD * sizeof(unsigned short));
    float* frames = (float*)alloc((size_t)Tn * Bsz * XPAD * sizeof(float));
    float* hA     = (float*)alloc((size_t)Bsz * Hsz * sizeof(float));
    float* hB     = (float*)alloc((size_t)Bsz * Hsz * sizeof(float));
    float* x0     = (float*)alloc((size_t)Bsz * XPAD * sizeof(float));
    float* x1     = (float*)alloc((size_t)Bsz * XPAD * sizeof(float));
    float* logit  = (float*)alloc((size_t)Bsz * sizeof(float));

    init_kernel<<<(Bsz * Hsz + 255) / 256, 256, 0, stream>>>(hA, logit, fc2_b);
    pack_weights<<<(3 * 1024 * KPAD + 255) / 256, 256, 0, stream>>>(w_ih, w_hh, wpack);
    pack_frames<<<(Tn * Bsz * XPAD + 255) / 256, 256, 0, stream>>>(enc, dec, frames);

    float* hc = hA;
    float* hn = hB;
    // Encoding pass: 74 GRU steps over frames
    for (int t = 0; t < Tn; ++t) {
        gru_step<<<256, 256, 0, stream>>>(hc, frames + (size_t)t * Bsz * XPAD, wpack, b_ih, b_hh, hn);
        float* tmp = hc; hc = hn; hn = tmp;
    }
    // Decoding pass: 74 autoregressive GRU steps + fc1/fc2 epilogue
    const float* xprev = frames;   // frames[0]
    float* xbufs[2] = {x0, x1};
    for (int d = 0; d < Tn; ++d) {
        gru_step<<<256, 256, 0, stream>>>(hc, xprev, wpack, b_ih, b_hh, hn);
        float* tmp = hc; hc = hn; hn = tmp;
        float* xo = xbufs[d & 1];
        fc1_step<<<1024, 256, 0, stream>>>(hc, xprev, fc1_w, fc1_b, fc2_w, xo, logit, d);
        xprev = xo;
    }
    final_kernel<<<4, 256, 0, stream>>>(logit, out);
}

// Round 2
// 4692.788 us; speedup vs baseline: 1.4798x; 1.4798x over previous
//
#include <hip/hip_runtime.h>
#include <hip/hip_bf16.h>

#define Bsz  1024
#define Hsz  1024
#define Isz  69
#define SRCn 50
#define Tn   74
#define KP   1152     // padded K = 1024 (h) + 128 (x)
#define XP   128      // bf16 x row pad
#define XPF  80       // fp32 x row pad (fc1 residual)

typedef short  short8 __attribute__((ext_vector_type(8)));
typedef float  f32x4  __attribute__((ext_vector_type(4)));
using ushort = unsigned short;

__device__ __forceinline__ ushort f2bf(float f) {
    unsigned u = __float_as_uint(f);
    return (ushort)((u + 0x7fffu + ((u >> 16) & 1u)) >> 16);  // RNE
}

// async global -> LDS, 16B per lane, lane i lands at ldsbase + 16*i
__device__ __forceinline__ void gld_lds16(const void* g, void* l) {
    __builtin_amdgcn_global_load_lds(
        (const __attribute__((address_space(1))) unsigned int*)g,
        (__attribute__((address_space(3))) unsigned int*)l, 16, 0, 0);
}

__global__ void init_k(float* __restrict__ hf, ushort* __restrict__ hbf,
                       float* __restrict__ logit, const float* __restrict__ fc2_b) {
    unsigned gid = blockIdx.x * 256 + threadIdx.x;
    if (gid < 1024u * 1024u) { hf[gid] = 0.f; hbf[gid] = 0; }
    if (gid < 1024u) logit[gid] = fc2_b[0];
}

// wpack[3072][1152] bf16 = [w_hh | w_ih | 0]; w1p[80][1024] bf16 (rows >=69 zero)
__global__ void pack_w(const float* __restrict__ w_ih, const float* __restrict__ w_hh,
                       const float* __restrict__ fc1_w,
                       ushort* __restrict__ wpack, ushort* __restrict__ w1p) {
    unsigned gid = blockIdx.x * 256 + threadIdx.x;
    const unsigned WN4 = 3072u * 288u;
    if (gid < WN4) {
        unsigned row = gid / 288u, c4 = (gid % 288u) * 4u;
        ushort4 o; ushort* po = (ushort*)&o;
#pragma unroll
        for (int e = 0; e < 4; ++e) {
            unsigned k = c4 + e; float v = 0.f;
            if (k < 1024u)       v = w_hh[(size_t)row * 1024u + k];
            else if (k < 1093u)  v = w_ih[(size_t)row * 69u + (k - 1024u)];
            po[e] = f2bf(v);
        }
        *(ushort4*)(wpack + (size_t)row * KP + c4) = o;
    } else if (gid < WN4 + 20480u) {
        unsigned g2 = gid - WN4;
        unsigned i = g2 / 256u, c4 = (g2 % 256u) * 4u;
        ushort4 o; ushort* po = (ushort*)&o;
#pragma unroll
        for (int e = 0; e < 4; ++e)
            po[e] = (i < 69u) ? f2bf(fc1_w[(size_t)i * 1024u + c4 + e]) : (ushort)0;
        *(ushort4*)(w1p + (size_t)i * 1024u + c4) = o;
    }
}

// frames_bf[74][1024][128] bf16 (zero-padded); x0f[1024][80] fp32 = frame0
__global__ void pack_f(const float* __restrict__ enc, const float* __restrict__ dec,
                       ushort* __restrict__ frames, float* __restrict__ x0f) {
    unsigned gid = blockIdx.x * 256 + threadIdx.x;
    const unsigned NF4 = 74u * 1024u * 32u;
    if (gid < NF4) {
        unsigned c4 = (gid & 31u) * 4u;
        unsigned b  = (gid >> 5) & 1023u;
        unsigned tf = gid >> 15;
        ushort4 o; ushort* po = (ushort*)&o;
#pragma unroll
        for (int e = 0; e < 4; ++e) {
            unsigned i = c4 + e; float v = 0.f;
            if (i < 69u)
                v = (tf < 50u) ? enc[((size_t)b * 50u + tf) * 69u + i]
                               : dec[((size_t)b * 24u + (tf - 50u)) * 69u + i];
            po[e] = f2bf(v);
        }
        *(ushort4*)(frames + (size_t)tf * 1024u * XP + (size_t)b * XP + c4) = o;
    } else if (gid < NF4 + 81920u) {
        unsigned g2 = gid - NF4;
        unsigned b = g2 / 80u, i = g2 % 80u;
        x0f[g2] = (i < 69u) ? enc[(size_t)b * 50u * 69u + i] : 0.f;
    }
}

// Fused GRU step. Grid 256 (XCD-swizzled 16bm x 16bn), block 256 (4 waves).
// A (=[h|x] bf16) staged in LDS via global_load_lds, XOR-swizzled, BK=128, dbuf.
// B (=wpack bf16) loaded direct global->register, depth-2 prefetch.
__launch_bounds__(256)
__global__ void gru_step(const ushort* __restrict__ hbf, const float* __restrict__ hf,
                         const ushort* __restrict__ xbf,
                         const ushort* __restrict__ wpack,
                         const float* __restrict__ b_ih, const float* __restrict__ b_hh,
                         float* __restrict__ hf_out, ushort* __restrict__ hbf_out)
{
    __shared__ __align__(16) ushort ldsA[2 * 8192];   // 2 x (64 rows x 128 bf16) = 32 KB
    const int t    = threadIdx.x;
    const int blk  = blockIdx.x;
    const int idx  = blk >> 3, xcd = blk & 7;
    const int bn   = xcd * 2 + (idx & 1);   // XCD keeps 2 bn-slices of wpack L2-hot
    const int bm   = idx >> 1;
    const int wave = t >> 6, lane = t & 63;
    const int quad = lane >> 4, l16 = lane & 15;

    f32x4 accR[4], accZ[4], accNH[4], accNI[4];
#pragma unroll
    for (int i = 0; i < 4; ++i) {
        accR[i] = (f32x4){0.f,0.f,0.f,0.f}; accZ[i] = (f32x4){0.f,0.f,0.f,0.f};
        accNH[i] = (f32x4){0.f,0.f,0.f,0.f}; accNI[i] = (f32x4){0.f,0.f,0.f,0.f};
    }

    // ---- A staging: wave w stages rows w*16..w*16+15, 4 issues of 1KB ----
    const int p_  = lane & 15;      // 16B position within 256B row
    const int rl_ = lane >> 4;      // row within 4-row issue group
    auto stageA = [&](int c, int buf) {
#pragma unroll
        for (int i = 0; i < 4; ++i) {
            int srow = wave * 16 + i * 4 + rl_;
            int cc   = p_ ^ (srow & 15);            // XOR swizzle
            const ushort* g;
            if (c < 8) g = hbf + (size_t)(bm * 64 + srow) * 1024 + c * 128 + cc * 8;
            else       g = xbf + (size_t)(bm * 64 + srow) * XP + cc * 8;
            gld_lds16(g, &ldsA[buf * 8192 + (wave * 16 + i * 4) * 128]);
        }
    };

    // ---- B direct-global pointers (per-lane row = n-col of this wave) ----
    const ushort* bp0 = wpack + (size_t)(       bn * 64 + wave * 16 + l16) * KP + quad * 8;
    const ushort* bp1 = wpack + (size_t)(1024 + bn * 64 + wave * 16 + l16) * KP + quad * 8;
    const ushort* bp2 = wpack + (size_t)(2048 + bn * 64 + wave * 16 + l16) * KP + quad * 8;

    short8 bq[2][3];
    bq[0][0] = *(const short8*)(bp0);      bq[0][1] = *(const short8*)(bp1);      bq[0][2] = *(const short8*)(bp2);
    bq[1][0] = *(const short8*)(bp0 + 32); bq[1][1] = *(const short8*)(bp1 + 32); bq[1][2] = *(const short8*)(bp2 + 32);

    stageA(0, 0);
    __syncthreads();

#define GRU_STAGE(AN)                                                              \
    {                                                                              \
        const ushort* ab = &ldsA[buf * 8192];                                      \
        _Pragma("unroll")                                                          \
        for (int kk = 0; kk < 4; ++kk) {                                           \
            const int t32 = c * 4 + kk;                                            \
            const int slot = t32 & 1;                                              \
            const int pos = ((kk * 4 + quad) ^ l16) * 8;                           \
            short8 a0 = *(const short8*)(ab + ( 0 + l16) * 128 + pos);             \
            short8 a1 = *(const short8*)(ab + (16 + l16) * 128 + pos);             \
            short8 a2 = *(const short8*)(ab + (32 + l16) * 128 + pos);             \
            short8 a3 = *(const short8*)(ab + (48 + l16) * 128 + pos);             \
            short8 b0 = bq[slot][0], b1 = bq[slot][1], b2 = bq[slot][2];           \
            if (t32 + 2 < 36) {                                                    \
                bq[slot][0] = *(const short8*)(bp0 + (t32 + 2) * 32);              \
                bq[slot][1] = *(const short8*)(bp1 + (t32 + 2) * 32);              \
                bq[slot][2] = *(const short8*)(bp2 + (t32 + 2) * 32);              \
            }                                                                      \
            accR[0] = __builtin_amdgcn_mfma_f32_16x16x32_bf16(a0, b0, accR[0],0,0,0); \
            accZ[0] = __builtin_amdgcn_mfma_f32_16x16x32_bf16(a0, b1, accZ[0],0,0,0); \
            AN[0]   = __builtin_amdgcn_mfma_f32_16x16x32_bf16(a0, b2, AN[0],0,0,0);   \
            accR[1] = __builtin_amdgcn_mfma_f32_16x16x32_bf16(a1, b0, accR[1],0,0,0); \
            accZ[1] = __builtin_amdgcn_mfma_f32_16x16x32_bf16(a1, b1, accZ[1],0,0,0); \
            AN[1]   = __builtin_amdgcn_mfma_f32_16x16x32_bf16(a1, b2, AN[1],0,0,0);   \
            accR[2] = __builtin_amdgcn_mfma_f32_16x16x32_bf16(a2, b0, accR[2],0,0,0); \
            accZ[2] = __builtin_amdgcn_mfma_f32_16x16x32_bf16(a2, b1, accZ[2],0,0,0); \
            AN[2]   = __builtin_amdgcn_mfma_f32_16x16x32_bf16(a2, b2, AN[2],0,0,0);   \
            accR[3] = __builtin_amdgcn_mfma_f32_16x16x32_bf16(a3, b0, accR[3],0,0,0); \
            accZ[3] = __builtin_amdgcn_mfma_f32_16x16x32_bf16(a3, b1, accZ[3],0,0,0); \
            AN[3]   = __builtin_amdgcn_mfma_f32_16x16x32_bf16(a3, b2, AN[3],0,0,0);   \
        }                                                                          \
    }

#pragma unroll 1
    for (int c = 0; c < 9; ++c) {
        if (c < 8) stageA(c + 1, (c + 1) & 1);
        const int buf = c & 1;
        if (c < 8) { GRU_STAGE(accNH) } else { GRU_STAGE(accNI) }
        __syncthreads();
    }
#undef GRU_STAGE

    // Epilogue. C/D layout: col(n)=lane&15, row(m)=quad*4+reg.
    const int j = bn * 64 + wave * 16 + l16;
    const float bir = b_ih[j],        bhr = b_hh[j];
    const float biz = b_ih[1024 + j], bhz = b_hh[1024 + j];
    const float bin_= b_ih[2048 + j], bhn = b_hh[2048 + j];
#pragma unroll
    for (int mt = 0; mt < 4; ++mt) {
#pragma unroll
        for (int r = 0; r < 4; ++r) {
            int m = bm * 64 + mt * 16 + quad * 4 + r;
            float gr = accR[mt][r] + bir + bhr;
            float gz = accZ[mt][r] + biz + bhz;
            float rg = 1.f / (1.f + __expf(-gr));
            float zg = 1.f / (1.f + __expf(-gz));
            float nx = accNI[mt][r] + bin_ + rg * (accNH[mt][r] + bhn);
            nx = fminf(30.f, fmaxf(-30.f, nx));
            float e  = __expf(-2.f * nx);
            float ng = (1.f - e) / (1.f + e);
            float hp = hf[(size_t)m * 1024 + j];
            float hn = (1.f - zg) * ng + zg * hp;
            hf_out[(size_t)m * 1024 + j]  = hn;
            hbf_out[(size_t)m * 1024 + j] = f2bf(hn);
        }
    }
}

// Decode epilogue as tiny MFMA GEMM: out[1024][69] = xprev + h@w1p.T + b1.
// Grid 80 (16 bm x 5 bn), block 256, no LDS, direct-global frags depth-4 prefetch.
__launch_bounds__(256)
__global__ void fc1_step(const ushort* __restrict__ hbf, const float* __restrict__ xprevf,
                         const ushort* __restrict__ w1p, const float* __restrict__ fc1_b,
                         const float* __restrict__ fc2_w,
                         float* __restrict__ xfout, ushort* __restrict__ xbfout,
                         float* __restrict__ logit, int step)
{
    const int t = threadIdx.x;
    const int bm = blockIdx.x & 15, bn = blockIdx.x >> 4;  // bn 0..4
    const int wave = t >> 6, lane = t & 63;
    const int quad = lane >> 4, l16 = lane & 15;

    const ushort* ap = hbf + (size_t)(bm * 64 + wave * 16 + l16) * 1024 + quad * 8;
    const ushort* bp = w1p + (size_t)(bn * 16 + l16) * 1024 + quad * 8;

    short8 aq[4], bq[4];
#pragma unroll
    for (int s = 0; s < 4; ++s) {
        aq[s] = *(const short8*)(ap + s * 32);
        bq[s] = *(const short8*)(bp + s * 32);
    }
    f32x4 acc = (f32x4){0.f, 0.f, 0.f, 0.f};
#pragma unroll
    for (int t32 = 0; t32 < 32; ++t32) {
        short8 a = aq[t32 & 3], b = bq[t32 & 3];
        if (t32 + 4 < 32) {
            aq[t32 & 3] = *(const short8*)(ap + (t32 + 4) * 32);
            bq[t32 & 3] = *(const short8*)(bp + (t32 + 4) * 32);
        }
        acc = __builtin_amdgcn_mfma_f32_16x16x32_bf16(a, b, acc, 0, 0, 0);
    }

    const int j = bn * 16 + l16;            // output col, <80
    const bool jv = j < Isz;
    const float b1v = jv ? fc1_b[j] : 0.f;
    const float w2v = jv ? fc2_w[step * Isz + j] : 0.f;
#pragma unroll
    for (int r = 0; r < 4; ++r) {
        int m = bm * 64 + wave * 16 + quad * 4 + r;
        float out = acc[r] + xprevf[(size_t)m * XPF + j] + b1v;
        xfout[(size_t)m * XPF + j] = out;
        xbfout[(size_t)m * XP + j] = f2bf(out);
        float lp = w2v * out;
        lp += __shfl_xor(lp, 8, 16);
        lp += __shfl_xor(lp, 4, 16);
        lp += __shfl_xor(lp, 2, 16);
        lp += __shfl_xor(lp, 1, 16);
        if (l16 == 0) atomicAdd(&logit[m], lp);
    }
    if (bn == 4) {  // zero-fill xbf cols 80..127 for next step's A staging
        uint4 z; z.x = 0; z.y = 0; z.z = 0; z.w = 0;
        for (int ii = t; ii < 64 * 6; ii += 256) {
            int r = ii / 6, ch = ii % 6;
            *(uint4*)(xbfout + (size_t)(bm * 64 + r) * XP + 80 + ch * 8) = z;
        }
    }
}

__global__ void final_k(const float* __restrict__ logit, float* __restrict__ out) {
    int i = blockIdx.x * 256 + threadIdx.x;
    if (i < Bsz) out[i] = 1.f / (1.f + __expf(-logit[i]));
}

extern "C" void kernel_launch(void* const* d_in, const int* in_sizes, int n_in,
                              void* d_out, int out_size, void* d_ws, size_t ws_size,
                              hipStream_t stream)
{
    const float* enc   = (const float*)d_in[0];
    const float* dec   = (const float*)d_in[1];
    const float* w_ih  = (const float*)d_in[2];
    const float* w_hh  = (const float*)d_in[3];
    const float* b_ih  = (const float*)d_in[4];
    const float* b_hh  = (const float*)d_in[5];
    const float* fc1_w = (const float*)d_in[6];
    const float* fc1_b = (const float*)d_in[7];
    const float* fc2_w = (const float*)d_in[8];
    const float* fc2_b = (const float*)d_in[9];
    float* out = (float*)d_out;

    char* ws = (char*)d_ws;
    size_t off = 0;
    auto alloc = [&](size_t bytes) -> void* {
        void* p = ws + off; off += (bytes + 255) & ~(size_t)255; return p;
    };
    ushort* wpack  = (ushort*)alloc((size_t)3072 * KP * 2);
    ushort* w1p    = (ushort*)alloc((size_t)80 * 1024 * 2);
    ushort* frames = (ushort*)alloc((size_t)Tn * 1024 * XP * 2);
    float*  x0f    = (float*) alloc((size_t)1024 * XPF * 4);
    float*  hfA    = (float*) alloc((size_t)1024 * 1024 * 4);
    float*  hfB    = (float*) alloc((size_t)1024 * 1024 * 4);
    ushort* hbfA   = (ushort*)alloc((size_t)1024 * 1024 * 2);
    ushort* hbfB   = (ushort*)alloc((size_t)1024 * 1024 * 2);
    float*  xfA    = (float*) alloc((size_t)1024 * XPF * 4);
    float*  xfB    = (float*) alloc((size_t)1024 * XPF * 4);
    ushort* xbfA   = (ushort*)alloc((size_t)1024 * XP * 2);
    ushort* xbfB   = (ushort*)alloc((size_t)1024 * XP * 2);
    float*  logit  = (float*) alloc((size_t)1024 * 4);

    init_k<<<4096, 256, 0, stream>>>(hfA, hbfA, logit, fc2_b);
    pack_w<<<3536, 256, 0, stream>>>(w_ih, w_hh, fc1_w, wpack, w1p);
    pack_f<<<9792, 256, 0, stream>>>(enc, dec, frames, x0f);

    float* hf_c = hfA;  float* hf_n = hfB;
    ushort* hb_c = hbfA; ushort* hb_n = hbfB;

    // Encoding pass
    for (int tt = 0; tt < Tn; ++tt) {
        gru_step<<<256, 256, 0, stream>>>(hb_c, hf_c, frames + (size_t)tt * 1024 * XP,
                                          wpack, b_ih, b_hh, hf_n, hb_n);
        float* tf = hf_c; hf_c = hf_n; hf_n = tf;
        ushort* tb = hb_c; hb_c = hb_n; hb_n = tb;
    }
    // Decoding pass (autoregressive)
    const float*  xpf = x0f;
    const ushort* xpb = frames;  // frame 0 bf16
    float*  xfo[2]  = {xfA, xfB};
    ushort* xbfo[2] = {xbfA, xbfB};
    for (int d = 0; d < Tn; ++d) {
        gru_step<<<256, 256, 0, stream>>>(hb_c, hf_c, xpb, wpack, b_ih, b_hh, hf_n, hb_n);
        float* tf = hf_c; hf_c = hf_n; hf_n = tf;
        ushort* tb = hb_c; hb_c = hb_n; hb_n = tb;
        fc1_step<<<80, 256, 0, stream>>>(hb_c, xpf, w1p, fc1_b, fc2_w,
                                         xfo[d & 1], xbfo[d & 1], logit, d);
        xpf = xfo[d & 1]; xpb = xbfo[d & 1];
    }
    final_k<<<4, 256, 0, stream>>>(logit, out);
}

// Round 3
// 4507.164 us; speedup vs baseline: 1.5407x; 1.0412x over previous
//
#include <hip/hip_runtime.h>
#include <hip/hip_bf16.h>

#define Bsz  1024
#define Hsz  1024
#define Isz  69
#define SRCn 50
#define Tn   74
#define KP   1152     // padded K = 1024 (h) + 128 (x)
#define XP   128      // bf16 x row pad
#define XPF  80       // fp32 x row pad (fc1 residual)

typedef short  short8 __attribute__((ext_vector_type(8)));
typedef float  f32x4  __attribute__((ext_vector_type(4)));
using ushort = unsigned short;

__device__ __forceinline__ ushort f2bf(float f) {
    unsigned u = __float_as_uint(f);
    return (ushort)((u + 0x7fffu + ((u >> 16) & 1u)) >> 16);  // RNE
}

// async global -> LDS, 16B per lane, lane i lands at ldsbase + 16*i
__device__ __forceinline__ void gld_lds16(const void* g, void* l) {
    __builtin_amdgcn_global_load_lds(
        (const __attribute__((address_space(1))) unsigned int*)g,
        (__attribute__((address_space(3))) unsigned int*)l, 16, 0, 0);
}

__global__ void init_k(float* __restrict__ hf, ushort* __restrict__ hbf,
                       float* __restrict__ logit, const float* __restrict__ fc2_b) {
    unsigned gid = blockIdx.x * 256 + threadIdx.x;
    if (gid < 1024u * 1024u) { hf[gid] = 0.f; hbf[gid] = 0; }
    if (gid < 1024u) logit[gid] = fc2_b[0];
}

// wpack[3072][1152] bf16 = [w_hh | w_ih | 0]; w1p[80][1024] bf16 (rows >=69 zero)
__global__ void pack_w(const float* __restrict__ w_ih, const float* __restrict__ w_hh,
                       const float* __restrict__ fc1_w,
                       ushort* __restrict__ wpack, ushort* __restrict__ w1p) {
    unsigned gid = blockIdx.x * 256 + threadIdx.x;
    const unsigned WN4 = 3072u * 288u;
    if (gid < WN4) {
        unsigned row = gid / 288u, c4 = (gid % 288u) * 4u;
        ushort4 o; ushort* po = (ushort*)&o;
#pragma unroll
        for (int e = 0; e < 4; ++e) {
            unsigned k = c4 + e; float v = 0.f;
            if (k < 1024u)       v = w_hh[(size_t)row * 1024u + k];
            else if (k < 1093u)  v = w_ih[(size_t)row * 69u + (k - 1024u)];
            po[e] = f2bf(v);
        }
        *(ushort4*)(wpack + (size_t)row * KP + c4) = o;
    } else if (gid < WN4 + 20480u) {
        unsigned g2 = gid - WN4;
        unsigned i = g2 / 256u, c4 = (g2 % 256u) * 4u;
        ushort4 o; ushort* po = (ushort*)&o;
#pragma unroll
        for (int e = 0; e < 4; ++e)
            po[e] = (i < 69u) ? f2bf(fc1_w[(size_t)i * 1024u + c4 + e]) : (ushort)0;
        *(ushort4*)(w1p + (size_t)i * 1024u + c4) = o;
    }
}

// frames_bf[74][1024][128] bf16 (zero-padded); x0f[1024][80] fp32 = frame0
__global__ void pack_f(const float* __restrict__ enc, const float* __restrict__ dec,
                       ushort* __restrict__ frames, float* __restrict__ x0f) {
    unsigned gid = blockIdx.x * 256 + threadIdx.x;
    const unsigned NF4 = 74u * 1024u * 32u;
    if (gid < NF4) {
        unsigned c4 = (gid & 31u) * 4u;
        unsigned b  = (gid >> 5) & 1023u;
        unsigned tf = gid >> 15;
        ushort4 o; ushort* po = (ushort*)&o;
#pragma unroll
        for (int e = 0; e < 4; ++e) {
            unsigned i = c4 + e; float v = 0.f;
            if (i < 69u)
                v = (tf < 50u) ? enc[((size_t)b * 50u + tf) * 69u + i]
                               : dec[((size_t)b * 24u + (tf - 50u)) * 69u + i];
            po[e] = f2bf(v);
        }
        *(ushort4*)(frames + (size_t)tf * 1024u * XP + (size_t)b * XP + c4) = o;
    } else if (gid < NF4 + 81920u) {
        unsigned g2 = gid - NF4;
        unsigned b = g2 / 80u, i = g2 % 80u;
        x0f[g2] = (i < 69u) ? enc[(size_t)b * 50u * 69u + i] : 0.f;
    }
}

// Fused GRU step. Grid 256 (XCD-swizzled 16bm x 16bn), block 512 = 8 waves.
// Waves (wk,wn): wn picks 16 n-cols, wk splits each BK=128 stage's 4 kk-slots
// 2+2 -> 2 waves/SIMD for latency hiding, B elements still loaded exactly once
// per block. Partial accs reduced through LDS at the end (3 barriers).
__launch_bounds__(512, 2)
__global__ void gru_step(const ushort* __restrict__ hbf, const float* __restrict__ hf,
                         const ushort* __restrict__ xbf,
                         const ushort* __restrict__ wpack,
                         const float* __restrict__ b_ih, const float* __restrict__ b_hh,
                         float* __restrict__ hf_out, ushort* __restrict__ hbf_out)
{
    __shared__ __align__(16) ushort ldsA[2 * 8192];   // 32 KB: 2 x (64 rows x 128 bf16)
    const int t    = threadIdx.x;
    const int blk  = blockIdx.x;
    const int idx  = blk >> 3, xcd = blk & 7;
    const int bn   = xcd * 2 + (idx & 1);   // XCD keeps 2 bn-slices of wpack L2-hot
    const int bm   = idx >> 1;
    const int wave = t >> 6, lane = t & 63;
    const int wk   = wave >> 2, wn = wave & 3;
    const int quad = lane >> 4, l16 = lane & 15;

    f32x4 accR[4], accZ[4], accNH[4], accNI[4];
#pragma unroll
    for (int i = 0; i < 4; ++i) {
        accR[i] = (f32x4){0.f,0.f,0.f,0.f}; accZ[i] = (f32x4){0.f,0.f,0.f,0.f};
        accNH[i] = (f32x4){0.f,0.f,0.f,0.f}; accNI[i] = (f32x4){0.f,0.f,0.f,0.f};
    }

    // ---- A staging: wave w stages rows w*8..w*8+7 (2 issues of 1KB) ----
    const int p_  = lane & 15;      // 16B chunk within 256B row
    const int rl_ = lane >> 4;      // row within 4-row issue group
    auto stageA = [&](int c, int buf) {
#pragma unroll
        for (int i2 = 0; i2 < 2; ++i2) {
            int srow = wave * 8 + i2 * 4 + rl_;
            int cc   = p_ ^ (srow & 15);            // XOR swizzle
            const ushort* g;
            if (c < 8) g = hbf + (size_t)(bm * 64 + srow) * 1024 + c * 128 + cc * 8;
            else       g = xbf + (size_t)(bm * 64 + srow) * XP + cc * 8;
            gld_lds16(g, &ldsA[buf * 8192 + (wave * 8 + i2 * 4) * 128]);
        }
    };

    // ---- B direct-global: wave (wk,wn) owns n-col wn*16+l16, k-slots 4c+2wk+{0,1} ----
    const ushort* bp0 = wpack + (size_t)(       bn * 64 + wn * 16 + l16) * KP + quad * 8 + wk * 64;
    const ushort* bp1 = bp0 + (size_t)1024 * KP;
    const ushort* bp2 = bp0 + (size_t)2048 * KP;

    short8 bq[2][3];
    bq[0][0] = *(const short8*)(bp0);      bq[0][1] = *(const short8*)(bp1);      bq[0][2] = *(const short8*)(bp2);
    bq[1][0] = *(const short8*)(bp0 + 32); bq[1][1] = *(const short8*)(bp1 + 32); bq[1][2] = *(const short8*)(bp2 + 32);

    stageA(0, 0);
    __syncthreads();

#define GRU_KK(AN)                                                                 \
    {                                                                              \
        const int g = (wk * 2 + kk) * 4 + quad;                                    \
        const int pos = (g ^ l16) * 8;                                             \
        short8 a0 = *(const short8*)(ab + ( 0 + l16) * 128 + pos);                 \
        short8 a1 = *(const short8*)(ab + (16 + l16) * 128 + pos);                 \
        short8 a2 = *(const short8*)(ab + (32 + l16) * 128 + pos);                 \
        short8 a3 = *(const short8*)(ab + (48 + l16) * 128 + pos);                 \
        short8 b0 = bq[kk][0], b1 = bq[kk][1], b2 = bq[kk][2];                     \
        if (c < 8) {                                                               \
            bq[kk][0] = *(const short8*)(bp0 + (c + 1) * 128 + kk * 32);           \
            bq[kk][1] = *(const short8*)(bp1 + (c + 1) * 128 + kk * 32);           \
            bq[kk][2] = *(const short8*)(bp2 + (c + 1) * 128 + kk * 32);           \
        }                                                                          \
        accR[0] = __builtin_amdgcn_mfma_f32_16x16x32_bf16(a0, b0, accR[0],0,0,0);  \
        accZ[0] = __builtin_amdgcn_mfma_f32_16x16x32_bf16(a0, b1, accZ[0],0,0,0);  \
        AN[0]   = __builtin_amdgcn_mfma_f32_16x16x32_bf16(a0, b2, AN[0],0,0,0);    \
        accR[1] = __builtin_amdgcn_mfma_f32_16x16x32_bf16(a1, b0, accR[1],0,0,0);  \
        accZ[1] = __builtin_amdgcn_mfma_f32_16x16x32_bf16(a1, b1, accZ[1],0,0,0);  \
        AN[1]   = __builtin_amdgcn_mfma_f32_16x16x32_bf16(a1, b2, AN[1],0,0,0);    \
        accR[2] = __builtin_amdgcn_mfma_f32_16x16x32_bf16(a2, b0, accR[2],0,0,0);  \
        accZ[2] = __builtin_amdgcn_mfma_f32_16x16x32_bf16(a2, b1, accZ[2],0,0,0);  \
        AN[2]   = __builtin_amdgcn_mfma_f32_16x16x32_bf16(a2, b2, AN[2],0,0,0);    \
        accR[3] = __builtin_amdgcn_mfma_f32_16x16x32_bf16(a3, b0, accR[3],0,0,0);  \
        accZ[3] = __builtin_amdgcn_mfma_f32_16x16x32_bf16(a3, b1, accZ[3],0,0,0);  \
        AN[3]   = __builtin_amdgcn_mfma_f32_16x16x32_bf16(a3, b2, AN[3],0,0,0);    \
    }

#pragma unroll 1
    for (int c = 0; c < 9; ++c) {
        if (c < 8) stageA(c + 1, (c + 1) & 1);
        const ushort* ab = &ldsA[(c & 1) * 8192];
        if (c < 8) {
#pragma unroll
            for (int kk = 0; kk < 2; ++kk) GRU_KK(accNH)
        } else {
#pragma unroll
            for (int kk = 0; kk < 2; ++kk) GRU_KK(accNI)
        }
        __syncthreads();
    }
#undef GRU_KK

    // ---- cross-wk reduction via LDS (f32x4, lane-consecutive = conflict-free) ----
    f32x4* red = (f32x4*)ldsA;                  // 2048 slots = 32 KB exactly
    const int rslot = wn * 64 + lane;
    if (wk == 1) {
#pragma unroll
        for (int mt = 0; mt < 4; ++mt) {
            red[mt * 256 + rslot]        = accR[mt];
            red[1024 + mt * 256 + rslot] = accZ[mt];
        }
    }
    __syncthreads();
    if (wk == 0) {
#pragma unroll
        for (int mt = 0; mt < 4; ++mt) {
            accR[mt] += red[mt * 256 + rslot];
            accZ[mt] += red[1024 + mt * 256 + rslot];
        }
    }
    __syncthreads();
    if (wk == 1) {
#pragma unroll
        for (int mt = 0; mt < 4; ++mt) {
            red[mt * 256 + rslot]        = accNH[mt];
            red[1024 + mt * 256 + rslot] = accNI[mt];
        }
    }
    __syncthreads();
    if (wk == 0) {
#pragma unroll
        for (int mt = 0; mt < 4; ++mt) {
            accNH[mt] += red[mt * 256 + rslot];
            accNI[mt] += red[1024 + mt * 256 + rslot];
        }
        // Epilogue. C/D layout: col(n)=lane&15, row(m)=quad*4+reg.
        const int j = bn * 64 + wn * 16 + l16;
        const float bir = b_ih[j],        bhr = b_hh[j];
        const float biz = b_ih[1024 + j], bhz = b_hh[1024 + j];
        const float bin_= b_ih[2048 + j], bhn = b_hh[2048 + j];
#pragma unroll
        for (int mt = 0; mt < 4; ++mt) {
#pragma unroll
            for (int r = 0; r < 4; ++r) {
                int m = bm * 64 + mt * 16 + quad * 4 + r;
                float gr = accR[mt][r] + bir + bhr;
                float gz = accZ[mt][r] + biz + bhz;
                float rg = 1.f / (1.f + __expf(-gr));
                float zg = 1.f / (1.f + __expf(-gz));
                float nx = accNI[mt][r] + bin_ + rg * (accNH[mt][r] + bhn);
                nx = fminf(30.f, fmaxf(-30.f, nx));
                float e  = __expf(-2.f * nx);
                float ng = (1.f - e) / (1.f + e);
                float hp = hf[(size_t)m * 1024 + j];
                float hn = (1.f - zg) * ng + zg * hp;
                hf_out[(size_t)m * 1024 + j]  = hn;
                hbf_out[(size_t)m * 1024 + j] = f2bf(hn);
            }
        }
    }
}

// Decode epilogue as tiny MFMA GEMM: out[1024][69] = xprev + h@w1p.T + b1.
// Grid 80 (16 bm x 5 bn), block 256, no LDS, direct-global frags depth-8 prefetch.
__launch_bounds__(256)
__global__ void fc1_step(const ushort* __restrict__ hbf, const float* __restrict__ xprevf,
                         const ushort* __restrict__ w1p, const float* __restrict__ fc1_b,
                         const float* __restrict__ fc2_w,
                         float* __restrict__ xfout, ushort* __restrict__ xbfout,
                         float* __restrict__ logit, int step)
{
    const int t = threadIdx.x;
    const int bm = blockIdx.x & 15, bn = blockIdx.x >> 4;  // bn 0..4
    const int wave = t >> 6, lane = t & 63;
    const int quad = lane >> 4, l16 = lane & 15;

    const ushort* ap = hbf + (size_t)(bm * 64 + wave * 16 + l16) * 1024 + quad * 8;
    const ushort* bp = w1p + (size_t)(bn * 16 + l16) * 1024 + quad * 8;

    short8 aq[8], bq[8];
#pragma unroll
    for (int s = 0; s < 8; ++s) {
        aq[s] = *(const short8*)(ap + s * 32);
        bq[s] = *(const short8*)(bp + s * 32);
    }
    f32x4 acc = (f32x4){0.f, 0.f, 0.f, 0.f};
#pragma unroll
    for (int t32 = 0; t32 < 32; ++t32) {
        short8 a = aq[t32 & 7], b = bq[t32 & 7];
        if (t32 + 8 < 32) {
            aq[t32 & 7] = *(const short8*)(ap + (t32 + 8) * 32);
            bq[t32 & 7] = *(const short8*)(bp + (t32 + 8) * 32);
        }
        acc = __builtin_amdgcn_mfma_f32_16x16x32_bf16(a, b, acc, 0, 0, 0);
    }

    const int j = bn * 16 + l16;            // output col, <80
    const bool jv = j < Isz;
    const float b1v = jv ? fc1_b[j] : 0.f;
    const float w2v = jv ? fc2_w[step * Isz + j] : 0.f;
#pragma unroll
    for (int r = 0; r < 4; ++r) {
        int m = bm * 64 + wave * 16 + quad * 4 + r;
        float out = acc[r] + xprevf[(size_t)m * XPF + j] + b1v;
        xfout[(size_t)m * XPF + j] = out;
        xbfout[(size_t)m * XP + j] = f2bf(out);
        float lp = w2v * out;
        lp += __shfl_xor(lp, 8, 16);
        lp += __shfl_xor(lp, 4, 16);
        lp += __shfl_xor(lp, 2, 16);
        lp += __shfl_xor(lp, 1, 16);
        if (l16 == 0) atomicAdd(&logit[m], lp);
    }
    if (bn == 4) {  // zero-fill xbf cols 80..127 for next step's A staging
        uint4 z; z.x = 0; z.y = 0; z.z = 0; z.w = 0;
        for (int ii = t; ii < 64 * 6; ii += 256) {
            int r = ii / 6, ch = ii % 6;
            *(uint4*)(xbfout + (size_t)(bm * 64 + r) * XP + 80 + ch * 8) = z;
        }
    }
}

__global__ void final_k(const float* __restrict__ logit, float* __restrict__ out) {
    int i = blockIdx.x * 256 + threadIdx.x;
    if (i < Bsz) out[i] = 1.f / (1.f + __expf(-logit[i]));
}

extern "C" void kernel_launch(void* const* d_in, const int* in_sizes, int n_in,
                              void* d_out, int out_size, void* d_ws, size_t ws_size,
                              hipStream_t stream)
{
    const float* enc   = (const float*)d_in[0];
    const float* dec   = (const float*)d_in[1];
    const float* w_ih  = (const float*)d_in[2];
    const float* w_hh  = (const float*)d_in[3];
    const float* b_ih  = (const float*)d_in[4];
    const float* b_hh  = (const float*)d_in[5];
    const float* fc1_w = (const float*)d_in[6];
    const float* fc1_b = (const float*)d_in[7];
    const float* fc2_w = (const float*)d_in[8];
    const float* fc2_b = (const float*)d_in[9];
    float* out = (float*)d_out;

    char* ws = (char*)d_ws;
    size_t off = 0;
    auto alloc = [&](size_t bytes) -> void* {
        void* p = ws + off; off += (bytes + 255) & ~(size_t)255; return p;
    };
    ushort* wpack  = (ushort*)alloc((size_t)3072 * KP * 2);
    ushort* w1p    = (ushort*)alloc((size_t)80 * 1024 * 2);
    ushort* frames = (ushort*)alloc((size_t)Tn * 1024 * XP * 2);
    float*  x0f    = (float*) alloc((size_t)1024 * XPF * 4);
    float*  hfA    = (float*) alloc((size_t)1024 * 1024 * 4);
    float*  hfB    = (float*) alloc((size_t)1024 * 1024 * 4);
    ushort* hbfA   = (ushort*)alloc((size_t)1024 * 1024 * 2);
    ushort* hbfB   = (ushort*)alloc((size_t)1024 * 1024 * 2);
    float*  xfA    = (float*) alloc((size_t)1024 * XPF * 4);
    float*  xfB    = (float*) alloc((size_t)1024 * XPF * 4);
    ushort* xbfA   = (ushort*)alloc((size_t)1024 * XP * 2);
    ushort* xbfB   = (ushort*)alloc((size_t)1024 * XP * 2);
    float*  logit  = (float*) alloc((size_t)1024 * 4);

    init_k<<<4096, 256, 0, stream>>>(hfA, hbfA, logit, fc2_b);
    pack_w<<<3536, 256, 0, stream>>>(w_ih, w_hh, fc1_w, wpack, w1p);
    pack_f<<<9792, 256, 0, stream>>>(enc, dec, frames, x0f);

    float* hf_c = hfA;  float* hf_n = hfB;
    ushort* hb_c = hbfA; ushort* hb_n = hbfB;

    // Encoding pass
    for (int tt = 0; tt < Tn; ++tt) {
        gru_step<<<256, 512, 0, stream>>>(hb_c, hf_c, frames + (size_t)tt * 1024 * XP,
                                          wpack, b_ih, b_hh, hf_n, hb_n);
        float* tf = hf_c; hf_c = hf_n; hf_n = tf;
        ushort* tb = hb_c; hb_c = hb_n; hb_n = tb;
    }
    // Decoding pass (autoregressive)
    const float*  xpf = x0f;
    const ushort* xpb = frames;  // frame 0 bf16
    float*  xfo[2]  = {xfA, xfB};
    ushort* xbfo[2] = {xbfA, xbfB};
    for (int d = 0; d < Tn; ++d) {
        gru_step<<<256, 512, 0, stream>>>(hb_c, hf_c, xpb, wpack, b_ih, b_hh, hf_n, hb_n);
        float* tf = hf_c; hf_c = hf_n; hf_n = tf;
        ushort* tb = hb_c; hb_c = hb_n; hb_n = tb;
        fc1_step<<<80, 256, 0, stream>>>(hb_c, xpf, w1p, fc1_b, fc2_w,
                                         xfo[d & 1], xbfo[d & 1], logit, d);
        xpf = xfo[d & 1]; xpb = xbfo[d & 1];
    }
    final_k<<<4, 256, 0, stream>>>(logit, out);
}